// Round 6
// baseline (419.754 us; speedup 1.0000x reference)
//
#include <hip/hip_runtime.h>
#include <hip/hip_bf16.h>

#define N_NODES 20000
#define N_EDGES 320000
#define HD 512

typedef __attribute__((ext_vector_type(8))) short bf16x8;
typedef __attribute__((ext_vector_type(4))) float f32x4;

// ---------- bf16 helpers ----------
__device__ inline ushort f2bf(float f) {
    uint u = __float_as_uint(f);
    uint r = (u + 0x7fffu + ((u >> 16) & 1u)) >> 16;
    return (ushort)r;
}
__device__ inline uint pack2(float a, float b) {
    return (uint)f2bf(a) | ((uint)f2bf(b) << 16);
}
__device__ inline float bflo(uint u) { return __uint_as_float(u << 16); }
__device__ inline float bfhi(uint u) { return __uint_as_float(u & 0xffff0000u); }

__device__ __forceinline__ void async_load16(const void* g, void* l) {
    __builtin_amdgcn_global_load_lds(
        (const __attribute__((address_space(1))) uint*)g,
        (__attribute__((address_space(3))) uint*)l,
        16, 0, 0);
}

// ---------- gemm tile: 128x128, global_load_lds, XOR swizzle (proven) -------
__device__ __forceinline__ void gemm_tile(const ushort* __restrict__ A,
                                          const ushort* __restrict__ Bt,
                                          ushort* __restrict__ C,
                                          int tile, char* smem) {
    short* As = (short*)smem;
    short* Bs = (short*)(smem + 128 * 32 * 2);
    const int tid = threadIdx.x;
    const int lane = tid & 63;
    const int wave = tid >> 6;
    const int l15 = lane & 15;
    const int q = lane >> 4;
    const int wrow = wave >> 1, wcol = wave & 1;
    const int row0 = (tile >> 2) * 128;
    const int col0 = (tile & 3) * 128;

    const int srow = lane >> 2;
    const int kc   = (lane & 3) ^ ((lane >> 3) & 3);
    const int sl   = (l15 >> 1) & 3;

    f32x4 acc[4][4] = {};

    for (int k0 = 0; k0 < HD; k0 += 32) {
        #pragma unroll
        for (int l = 0; l < 2; ++l) {
            const int rbase = wave * 32 + l * 16;
            const ushort* ga = &A [(size_t)(row0 + rbase + srow) * HD + k0 + kc * 8];
            const ushort* gb = &Bt[(size_t)(col0 + rbase + srow) * HD + k0 + kc * 8];
            async_load16(ga, &As[rbase * 32]);
            async_load16(gb, &Bs[rbase * 32]);
        }
        __syncthreads();
        bf16x8 aF[4], bF[4];
        #pragma unroll
        for (int i = 0; i < 4; ++i)
            aF[i] = *(bf16x8*)&As[(wrow * 64 + i * 16 + l15) * 32 + (q ^ sl) * 8];
        #pragma unroll
        for (int j = 0; j < 4; ++j)
            bF[j] = *(bf16x8*)&Bs[(wcol * 64 + j * 16 + l15) * 32 + (q ^ sl) * 8];
        #pragma unroll
        for (int i = 0; i < 4; ++i)
            #pragma unroll
            for (int j = 0; j < 4; ++j)
                acc[i][j] = __builtin_amdgcn_mfma_f32_16x16x32_bf16(aF[i], bF[j], acc[i][j], 0, 0, 0);
        __syncthreads();
    }
    #pragma unroll
    for (int i = 0; i < 4; ++i) {
        #pragma unroll
        for (int r = 0; r < 4; ++r) {
            int gr = row0 + wrow * 64 + i * 16 + q * 4 + r;
            if (gr < N_NODES) {
                #pragma unroll
                for (int j = 0; j < 4; ++j) {
                    int gc = col0 + wcol * 64 + j * 16 + l15;
                    C[(size_t)gr * HD + gc] = f2bf(acc[i][j][r]);
                }
            }
        }
    }
}

// ---------- pool partial (proven) ----------
__device__ __forceinline__ void pool_part(const ushort* __restrict__ h,
                                          float* __restrict__ pmax,
                                          float* __restrict__ psum,
                                          int pb, char* smem) {
    float* lmx = (float*)smem;           // 2048 floats
    float* lsm = lmx + 2048;             // 2048 floats
    const int tid = threadIdx.x;
    const int wave = tid >> 6, lane = tid & 63;
    const uint4* h4 = (const uint4*)h;
    float m[8] = {}, sm[8] = {};
    for (int r = pb * 4 + wave; r < N_NODES; r += 1024) {
        uint4 v = h4[(size_t)r * 64 + lane];
        m[0] = fmaxf(m[0], bflo(v.x)); sm[0] += bflo(v.x);
        m[1] = fmaxf(m[1], bfhi(v.x)); sm[1] += bfhi(v.x);
        m[2] = fmaxf(m[2], bflo(v.y)); sm[2] += bflo(v.y);
        m[3] = fmaxf(m[3], bfhi(v.y)); sm[3] += bfhi(v.y);
        m[4] = fmaxf(m[4], bflo(v.z)); sm[4] += bflo(v.z);
        m[5] = fmaxf(m[5], bfhi(v.z)); sm[5] += bfhi(v.z);
        m[6] = fmaxf(m[6], bflo(v.w)); sm[6] += bflo(v.w);
        m[7] = fmaxf(m[7], bfhi(v.w)); sm[7] += bfhi(v.w);
    }
    #pragma unroll
    for (int i = 0; i < 8; ++i) {
        lmx[wave * 512 + lane * 8 + i] = m[i];
        lsm[wave * 512 + lane * 8 + i] = sm[i];
    }
    __syncthreads();
    #pragma unroll
    for (int cc = 0; cc < 2; ++cc) {
        int ch = tid * 2 + cc;
        float mx = fmaxf(fmaxf(lmx[ch], lmx[512 + ch]),
                         fmaxf(lmx[1024 + ch], lmx[1536 + ch]));
        float sv = (lsm[ch] + lsm[512 + ch]) + (lsm[1024 + ch] + lsm[1536 + ch]);
        atomicMax((int*)&pmax[ch], __float_as_int(mx));   // values >= 0
        atomicAdd(&psum[ch], sv);
    }
}

// ---------- prep: cvt x | wt transpose | zero deg/pmax/psum ----------
#define NB_CVT 5000
#define NB_WT  192
#define NB_ZD  79
__global__ __launch_bounds__(256) void prep_k(const float* __restrict__ x,
                                              ushort* __restrict__ xb,
                                              const float* __restrict__ W1,
                                              const float* __restrict__ W2,
                                              const float* __restrict__ W3,
                                              ushort* __restrict__ T1,
                                              ushort* __restrict__ T2,
                                              ushort* __restrict__ T3,
                                              int* __restrict__ deg,
                                              float* __restrict__ pmax,
                                              float* __restrict__ psum) {
    __shared__ float t[64][65];
    const int b = blockIdx.x;
    const int tid = threadIdx.x;
    if (b < NB_CVT) {
        int c = b * 256 + tid;
        const float4* p = (const float4*)x + (size_t)c * 2;
        float4 a = p[0], q = p[1];
        uint4 o;
        o.x = pack2(a.x, a.y); o.y = pack2(a.z, a.w);
        o.z = pack2(q.x, q.y); o.w = pack2(q.z, q.w);
        ((uint4*)xb)[c] = o;
    } else if (b < NB_CVT + NB_WT) {
        int idx = b - NB_CVT;
        int layer = idx >> 6, rem = idx & 63;
        const float* W = (layer == 0) ? W1 : (layer == 1) ? W2 : W3;
        ushort* T      = (layer == 0) ? T1 : (layer == 1) ? T2 : T3;
        int kb = (rem >> 3) * 64, nb = (rem & 7) * 64;
        int c = tid & 63, r4 = tid >> 6;
        #pragma unroll
        for (int l = 0; l < 16; ++l) {
            int r = l * 4 + r4;
            t[r][c] = W[(size_t)(kb + r) * HD + nb + c];
        }
        __syncthreads();
        #pragma unroll
        for (int l = 0; l < 16; ++l) {
            int r = l * 4 + r4;
            T[(size_t)(nb + r) * HD + kb + c] = f2bf(t[c][r]);
        }
    } else if (b < NB_CVT + NB_WT + NB_ZD) {
        int i = (b - NB_CVT - NB_WT) * 256 + tid;
        if (i < N_NODES) deg[i] = 0;
    } else if (b < NB_CVT + NB_WT + NB_ZD + 6) {
        int i = (b - NB_CVT - NB_WT - NB_ZD) * 256 + tid;
        pmax[i] = 0.f;
    } else {
        int i = (b - NB_CVT - NB_WT - NB_ZD - 6) * 256 + tid;
        psum[i] = 0.f;
    }
}

// ---------- fused1: gemm layer1 (0..627) || hist (628..1877) ----------
__global__ __launch_bounds__(256) void fused1_k(const ushort* __restrict__ xb,
                                                const ushort* __restrict__ wt1,
                                                ushort* __restrict__ s,
                                                const int* __restrict__ rows,
                                                int* __restrict__ deg) {
    __shared__ __align__(16) char smem[16384];
    const int b = blockIdx.x;
    if (b < 628) {
        gemm_tile(xb, wt1, s, b, smem);
    } else {
        int e = (b - 628) * 256 + threadIdx.x;   // 1250*256 == N_EDGES exactly
        atomicAdd(&deg[rows[e]], 1);
    }
}

// ---------- scan: one workgroup, 16 waves, shuffle; + degree histogram ------
// Also builds the 256-bucket degree histogram (clamped) and its exclusive
// scan -> bcur[256], used by fill_k's counting-sort scatter into perm[].
__global__ __launch_bounds__(1024) void scan_k(const int* __restrict__ deg,
                                               int* __restrict__ rowstart,
                                               int* __restrict__ cursor,
                                               int* __restrict__ bcur) {
    __shared__ int wsum[16];
    __shared__ int hist[256];
    const int tid = threadIdx.x;
    const int lane = tid & 63, wv = tid >> 6;
    if (tid < 256) hist[tid] = 0;
    __syncthreads();
    int carry = 0;
    for (int base = 0; base < N_NODES; base += 1024) {
        int i = base + tid;
        int v = (i < N_NODES) ? deg[i] : 0;
        if (i < N_NODES) atomicAdd(&hist[v < 255 ? v : 255], 1);
        int incl = v;
        #pragma unroll
        for (int off = 1; off < 64; off <<= 1) {
            int t = __shfl_up(incl, off, 64);
            if (lane >= off) incl += t;
        }
        if (lane == 63) wsum[wv] = incl;
        __syncthreads();
        int woff = 0, tot = 0;
        #pragma unroll
        for (int w = 0; w < 16; ++w) {
            int sv = wsum[w];
            if (w < wv) woff += sv;
            tot += sv;
        }
        if (i < N_NODES) {
            int ex = carry + woff + incl - v;
            rowstart[i] = ex;
            cursor[i]   = ex;
        }
        carry += tot;
        __syncthreads();
    }
    if (tid == 0) {
        rowstart[N_NODES] = carry;
        int a = 0;
        for (int d = 0; d < 256; ++d) { bcur[d] = a; a += hist[d]; }
    }
}

// ---------- fill CSR (edges) + counting-sort scatter (rows) ----------------
#define FILL_EB 1250
#define FILL_RB 79
__global__ void fill_k(const int* __restrict__ rows, const int* __restrict__ cols,
                       const float* __restrict__ vals, int* __restrict__ cursor,
                       int2* __restrict__ csr_cv, const int* __restrict__ deg,
                       int* __restrict__ bcur, int* __restrict__ perm) {
    const int b = blockIdx.x;
    const int tid = threadIdx.x;
    if (b < FILL_EB) {
        int e = b * 256 + tid;                    // 1250*256 == N_EDGES
        int p = atomicAdd(&cursor[rows[e]], 1);
        csr_cv[p] = make_int2(cols[e], __float_as_int(vals[e]));
    } else {
        int r = (b - FILL_EB) * 256 + tid;
        if (r < N_NODES) {
            int d = deg[r]; if (d > 255) d = 255;
            int p = atomicAdd(&bcur[d], 1);
            perm[p] = r;                          // ascending degree order
        }
    }
}

// ---------- aggregate v6: sliced + pinned + pipelined + degree-sorted -------
// r5 post-mortem: 43us @ occupancy 45%, nothing saturated -> imbalance.
// (a) within-wave: 8 lockstep groups run max(group degree) trips, ~35% of
// trips exec-masked (Poisson degree spread); (b) across blocks: random degree
// mixes -> long ramp-down tail. Fix: counting-sort rows by degree (perm[]);
// groups take CONSECUTIVE sorted rows (equal degrees -> lockstep waste ~0);
// chunks consumed in DESCENDING degree order (LPT: long blocks first, short
// low-degree blocks pack the tail). Gather structure unchanged (proven).
__device__ inline void fma8(float* acc, uint4 v, float w) {
    acc[0] += w * bflo(v.x); acc[1] += w * bfhi(v.x);
    acc[2] += w * bflo(v.y); acc[3] += w * bfhi(v.y);
    acc[4] += w * bflo(v.z); acc[5] += w * bfhi(v.z);
    acc[6] += w * bflo(v.w); acc[7] += w * bfhi(v.w);
}

#define RPG 2                                    // rows per 8-lane group
#define AGG_RPB (32 * RPG)                       // 64 rows per block
#define AGG_CHUNKS ((N_NODES + AGG_RPB - 1) / AGG_RPB)   // 313
#define AGG_BLOCKS (8 * AGG_CHUNKS)              // 2504

__global__ __launch_bounds__(256) void agg_k(const ushort* __restrict__ s,
                                             const int* __restrict__ rowstart,
                                             const int2* __restrict__ csr_cv,
                                             const int* __restrict__ perm,
                                             const float* __restrict__ bias,
                                             ushort* __restrict__ hout) {
    const int slice = blockIdx.x & 7;            // XCD-pinned channel slice
    const int cidx  = (AGG_CHUNKS - 1) - (int)(blockIdx.x >> 3);  // LPT order
    const int wave = threadIdx.x >> 6, lane = threadIdx.x & 63;
    const int g = lane >> 3, sub = lane & 7;     // group, 16B channel chunk
    const uint4* s4 = (const uint4*)s;
    const size_t sbase = (size_t)slice * 8 + sub;
    uint4* houtp = (uint4*)hout + slice * 8 + sub;
    const float4 b0 = ((const float4*)bias)[slice * 16 + sub * 2];
    const float4 b1 = ((const float4*)bias)[slice * 16 + sub * 2 + 1];
    const int ibase = cidx * AGG_RPB + wave * (8 * RPG) + g * RPG;

    #pragma unroll
    for (int rr = 0; rr < RPG; ++rr) {
        const int idx = ibase + rr;
        int row = 0, beg = 0, end = 0;
        if (idx < N_NODES) {                     // padded tail rows: no work
            row = perm[idx];                     // degree-sorted assignment
            beg = rowstart[row];
            end = rowstart[row + 1];
        }
        float acc[8] = {};
        int j = beg;
        int2 m0, m1, m2, m3;
        if (j < end) {                           // prime the meta pipeline
            m0 = csr_cv[j];
            m1 = csr_cv[(j + 1 < end) ? j + 1 : end - 1];
            m2 = csr_cv[(j + 2 < end) ? j + 2 : end - 1];
            m3 = csr_cv[(j + 3 < end) ? j + 3 : end - 1];
        }
        while (j < end) {
            const int jn = j + 4;
            const int cl = end - 1;
            // prefetch next trip's metadata (clamped; overlaps the gathers)
            int2 n0 = csr_cv[(jn     < end) ? jn     : cl];
            int2 n1 = csr_cv[(jn + 1 < end) ? jn + 1 : cl];
            int2 n2 = csr_cv[(jn + 2 < end) ? jn + 2 : cl];
            int2 n3 = csr_cv[(jn + 3 < end) ? jn + 3 : cl];
            // 4 independent 128B gathers in flight per group
            uint4 v0 = s4[(size_t)m0.x * 64 + sbase];
            uint4 v1 = s4[(size_t)m1.x * 64 + sbase];
            uint4 v2 = s4[(size_t)m2.x * 64 + sbase];
            uint4 v3 = s4[(size_t)m3.x * 64 + sbase];
            float w0 = __int_as_float(m0.y);     // j < end always valid
            float w1 = (j + 1 < end) ? __int_as_float(m1.y) : 0.f;
            float w2 = (j + 2 < end) ? __int_as_float(m2.y) : 0.f;
            float w3 = (j + 3 < end) ? __int_as_float(m3.y) : 0.f;
            fma8(acc, v0, w0);
            fma8(acc, v1, w1);
            fma8(acc, v2, w2);
            fma8(acc, v3, w3);
            m0 = n0; m1 = n1; m2 = n2; m3 = n3;
            j = jn;
        }
        if (idx < N_NODES) {                     // flush row (8 lanes = 128B)
            uint4 ov;
            ov.x = pack2(fmaxf(acc[0] + b0.x, 0.f), fmaxf(acc[1] + b0.y, 0.f));
            ov.y = pack2(fmaxf(acc[2] + b0.z, 0.f), fmaxf(acc[3] + b0.w, 0.f));
            ov.z = pack2(fmaxf(acc[4] + b1.x, 0.f), fmaxf(acc[5] + b1.y, 0.f));
            ov.w = pack2(fmaxf(acc[6] + b1.z, 0.f), fmaxf(acc[7] + b1.w, 0.f));
            houtp[(size_t)row * 64] = ov;
        }
    }
}

// ---------- fused gemm || pool (both read-only on h; proven) ----------
__global__ __launch_bounds__(256) void fusedgp_k(const ushort* __restrict__ h,
                                                 const ushort* __restrict__ wt,
                                                 ushort* __restrict__ s,
                                                 float* __restrict__ pmax,
                                                 float* __restrict__ psum) {
    __shared__ __align__(16) char smem[16384];
    const int b = blockIdx.x;
    if (b < 628) gemm_tile(h, wt, s, b, smem);
    else         pool_part(h, pmax, psum, b - 628, smem);
}

// ---------- standalone pool (layer 3) ----------
__global__ __launch_bounds__(256) void pool_k(const ushort* __restrict__ h,
                                              float* __restrict__ pmax,
                                              float* __restrict__ psum) {
    __shared__ __align__(16) char smem[16384];
    pool_part(h, pmax, psum, blockIdx.x, smem);
}

// ---------- head MLP + log_softmax (1024 threads, split-k; proven) ----------
__global__ __launch_bounds__(1024) void mlp_k(const float* __restrict__ pool_max,
                                              const float* __restrict__ pool_sum,
                                              const float* __restrict__ l1W,
                                              const float* __restrict__ l1b,
                                              const float* __restrict__ l2W,
                                              const float* __restrict__ l2b,
                                              const float* __restrict__ l3W,
                                              const float* __restrict__ l3b,
                                              float* __restrict__ out) {
    __shared__ float g[1024];
    __shared__ float part[1024];
    __shared__ float a1[128];
    __shared__ float a2[64];
    __shared__ float a3[10];
    const int tid = threadIdx.x;
    if (tid < 512) {
        g[tid]       = pool_max[tid] + pool_max[512 + tid] + pool_max[1024 + tid];
        g[512 + tid] = (pool_sum[tid] + pool_sum[512 + tid] + pool_sum[1024 + tid]) *
                       (1.0f / N_NODES);
    }
    __syncthreads();
    {
        int ch = tid & 127, sl = tid >> 7;
        float acc = (sl == 0) ? l1b[ch] : 0.f;
        int k0 = sl * 128;
        #pragma unroll 4
        for (int k = k0; k < k0 + 128; ++k) acc += g[k] * l1W[k * 128 + ch];
        part[tid] = acc;
    }
    __syncthreads();
    if (tid < 128) {
        float a = part[tid];
        #pragma unroll
        for (int ss = 1; ss < 8; ++ss) a += part[tid + ss * 128];
        a1[tid] = fmaxf(a, 0.f);
    }
    __syncthreads();
    if (tid < 512) {
        int ch = tid & 63, sl = tid >> 6;
        float acc = (sl == 0) ? l2b[ch] : 0.f;
        int k0 = sl * 16;
        #pragma unroll
        for (int k = k0; k < k0 + 16; ++k) acc += a1[k] * l2W[k * 64 + ch];
        part[tid] = acc;
    }
    __syncthreads();
    if (tid < 64) {
        float a = part[tid];
        #pragma unroll
        for (int ss = 1; ss < 8; ++ss) a += part[tid + ss * 64];
        a2[tid] = fmaxf(a, 0.f);
    }
    __syncthreads();
    if (tid < 10) {
        float acc = l3b[tid];
        for (int k = 0; k < 64; ++k) acc += a2[k] * l3W[k * 10 + tid];
        a3[tid] = acc;
    }
    __syncthreads();
    if (tid == 0) {
        float m = a3[0];
        for (int j = 1; j < 10; ++j) m = fmaxf(m, a3[j]);
        float ssum = 0.f;
        for (int j = 0; j < 10; ++j) ssum += expf(a3[j] - m);
        float lse = m + logf(ssum);
        for (int j = 0; j < 10; ++j) out[j] = a3[j] - lse;
    }
}

extern "C" void kernel_launch(void* const* d_in, const int* in_sizes, int n_in,
                              void* d_out, int out_size, void* d_ws, size_t ws_size,
                              hipStream_t stream) {
    const float* x    = (const float*)d_in[0];
    const int*   rows = (const int*)  d_in[1];
    const int*   cols = (const int*)  d_in[2];
    const float* vals = (const float*)d_in[3];
    const float* W1   = (const float*)d_in[4];
    const float* b1   = (const float*)d_in[5];
    const float* W2   = (const float*)d_in[6];
    const float* b2   = (const float*)d_in[7];
    const float* W3   = (const float*)d_in[8];
    const float* b3   = (const float*)d_in[9];
    const float* l1W  = (const float*)d_in[10];
    const float* l1b  = (const float*)d_in[11];
    const float* l2W  = (const float*)d_in[12];
    const float* l2b  = (const float*)d_in[13];
    const float* l3W  = (const float*)d_in[14];
    const float* l3b  = (const float*)d_in[15];
    float* out = (float*)d_out;

    char* ws = (char*)d_ws;
    size_t off = 0;
    auto alloc = [&](size_t bytes) {
        void* p = ws + off;
        off += (bytes + 255) & ~(size_t)255;
        return p;
    };
    ushort* xb       = (ushort*)alloc((size_t)N_NODES * HD * 2);
    ushort* s        = (ushort*)alloc((size_t)N_NODES * HD * 2);
    ushort* hb       = (ushort*)alloc((size_t)N_NODES * HD * 2);
    ushort* wt1      = (ushort*)alloc((size_t)HD * HD * 2);
    ushort* wt2      = (ushort*)alloc((size_t)HD * HD * 2);
    ushort* wt3      = (ushort*)alloc((size_t)HD * HD * 2);
    int*    deg      = (int*)   alloc((size_t)N_NODES * 4);
    float*  pmax     = (float*) alloc((size_t)3 * 512 * 4);
    float*  psum     = (float*) alloc((size_t)3 * 512 * 4);
    int*    rowstart = (int*)   alloc((size_t)(N_NODES + 1) * 4);
    int*    cursor   = (int*)   alloc((size_t)N_NODES * 4);
    int2*   csr_cv   = (int2*)  alloc((size_t)N_EDGES * 8);
    int*    bcur     = (int*)   alloc((size_t)256 * 4);
    int*    perm     = (int*)   alloc((size_t)N_NODES * 4);
    (void)ws_size; (void)in_sizes; (void)n_in; (void)out_size;

    // 1: prep (cvt + wt + zero deg/pmax/psum)
    prep_k<<<NB_CVT + NB_WT + NB_ZD + 12, 256, 0, stream>>>(
        x, xb, W1, W2, W3, wt1, wt2, wt3, deg, pmax, psum);
    // 2: gemm1 || hist
    fused1_k<<<628 + 1250, 256, 0, stream>>>(xb, wt1, s, rows, deg);
    // 3: scan (+ degree hist -> bcur)
    scan_k<<<1, 1024, 0, stream>>>(deg, rowstart, cursor, bcur);
    // 4: fill CSR || counting-sort scatter -> perm
    fill_k<<<FILL_EB + FILL_RB, 256, 0, stream>>>(rows, cols, vals, cursor,
                                                  csr_cv, deg, bcur, perm);
    // 5: agg1
    agg_k<<<AGG_BLOCKS, 256, 0, stream>>>(s, rowstart, csr_cv, perm, b1, hb);
    // 6: gemm2 || pool1
    fusedgp_k<<<628 + 256, 256, 0, stream>>>(hb, wt2, s, pmax, psum);
    // 7: agg2
    agg_k<<<AGG_BLOCKS, 256, 0, stream>>>(s, rowstart, csr_cv, perm, b2, hb);
    // 8: gemm3 || pool2
    fusedgp_k<<<628 + 256, 256, 0, stream>>>(hb, wt3, s, pmax + 512, psum + 512);
    // 9: agg3
    agg_k<<<AGG_BLOCKS, 256, 0, stream>>>(s, rowstart, csr_cv, perm, b3, hb);
    // 10: pool3
    pool_k<<<256, 256, 0, stream>>>(hb, pmax + 1024, psum + 1024);
    // 11: mlp head
    mlp_k<<<1, 1024, 0, stream>>>(pmax, psum, l1W, l1b, l2W, l2b, l3W, l3b, out);
}

// Round 7
// 381.614 us; speedup vs baseline: 1.0999x; 1.0999x over previous
//
#include <hip/hip_runtime.h>
#include <hip/hip_bf16.h>

#define N_NODES 20000
#define N_EDGES 320000
#define HD 512

typedef __attribute__((ext_vector_type(8))) short bf16x8;
typedef __attribute__((ext_vector_type(4))) float f32x4;

// ---------- bf16 helpers ----------
__device__ inline ushort f2bf(float f) {
    uint u = __float_as_uint(f);
    uint r = (u + 0x7fffu + ((u >> 16) & 1u)) >> 16;
    return (ushort)r;
}
__device__ inline uint pack2(float a, float b) {
    return (uint)f2bf(a) | ((uint)f2bf(b) << 16);
}
__device__ inline float bflo(uint u) { return __uint_as_float(u << 16); }
__device__ inline float bfhi(uint u) { return __uint_as_float(u & 0xffff0000u); }

__device__ __forceinline__ void async_load16(const void* g, void* l) {
    __builtin_amdgcn_global_load_lds(
        (const __attribute__((address_space(1))) uint*)g,
        (__attribute__((address_space(3))) uint*)l,
        16, 0, 0);
}

// ---------- gemm tile: 128x128, global_load_lds, XOR swizzle (proven) -------
__device__ __forceinline__ void gemm_tile(const ushort* __restrict__ A,
                                          const ushort* __restrict__ Bt,
                                          ushort* __restrict__ C,
                                          int tile, char* smem) {
    short* As = (short*)smem;
    short* Bs = (short*)(smem + 128 * 32 * 2);
    const int tid = threadIdx.x;
    const int lane = tid & 63;
    const int wave = tid >> 6;
    const int l15 = lane & 15;
    const int q = lane >> 4;
    const int wrow = wave >> 1, wcol = wave & 1;
    const int row0 = (tile >> 2) * 128;
    const int col0 = (tile & 3) * 128;

    const int srow = lane >> 2;
    const int kc   = (lane & 3) ^ ((lane >> 3) & 3);
    const int sl   = (l15 >> 1) & 3;

    f32x4 acc[4][4] = {};

    for (int k0 = 0; k0 < HD; k0 += 32) {
        #pragma unroll
        for (int l = 0; l < 2; ++l) {
            const int rbase = wave * 32 + l * 16;
            const ushort* ga = &A [(size_t)(row0 + rbase + srow) * HD + k0 + kc * 8];
            const ushort* gb = &Bt[(size_t)(col0 + rbase + srow) * HD + k0 + kc * 8];
            async_load16(ga, &As[rbase * 32]);
            async_load16(gb, &Bs[rbase * 32]);
        }
        __syncthreads();
        bf16x8 aF[4], bF[4];
        #pragma unroll
        for (int i = 0; i < 4; ++i)
            aF[i] = *(bf16x8*)&As[(wrow * 64 + i * 16 + l15) * 32 + (q ^ sl) * 8];
        #pragma unroll
        for (int j = 0; j < 4; ++j)
            bF[j] = *(bf16x8*)&Bs[(wcol * 64 + j * 16 + l15) * 32 + (q ^ sl) * 8];
        #pragma unroll
        for (int i = 0; i < 4; ++i)
            #pragma unroll
            for (int j = 0; j < 4; ++j)
                acc[i][j] = __builtin_amdgcn_mfma_f32_16x16x32_bf16(aF[i], bF[j], acc[i][j], 0, 0, 0);
        __syncthreads();
    }
    #pragma unroll
    for (int i = 0; i < 4; ++i) {
        #pragma unroll
        for (int r = 0; r < 4; ++r) {
            int gr = row0 + wrow * 64 + i * 16 + q * 4 + r;
            if (gr < N_NODES) {
                #pragma unroll
                for (int j = 0; j < 4; ++j) {
                    int gc = col0 + wcol * 64 + j * 16 + l15;
                    C[(size_t)gr * HD + gc] = f2bf(acc[i][j][r]);
                }
            }
        }
    }
}

// ---------- pool partial (proven) ----------
__device__ __forceinline__ void pool_part(const ushort* __restrict__ h,
                                          float* __restrict__ pmax,
                                          float* __restrict__ psum,
                                          int pb, char* smem) {
    float* lmx = (float*)smem;           // 2048 floats
    float* lsm = lmx + 2048;             // 2048 floats
    const int tid = threadIdx.x;
    const int wave = tid >> 6, lane = tid & 63;
    const uint4* h4 = (const uint4*)h;
    float m[8] = {}, sm[8] = {};
    for (int r = pb * 4 + wave; r < N_NODES; r += 1024) {
        uint4 v = h4[(size_t)r * 64 + lane];
        m[0] = fmaxf(m[0], bflo(v.x)); sm[0] += bflo(v.x);
        m[1] = fmaxf(m[1], bfhi(v.x)); sm[1] += bfhi(v.x);
        m[2] = fmaxf(m[2], bflo(v.y)); sm[2] += bflo(v.y);
        m[3] = fmaxf(m[3], bfhi(v.y)); sm[3] += bfhi(v.y);
        m[4] = fmaxf(m[4], bflo(v.z)); sm[4] += bflo(v.z);
        m[5] = fmaxf(m[5], bfhi(v.z)); sm[5] += bfhi(v.z);
        m[6] = fmaxf(m[6], bflo(v.w)); sm[6] += bflo(v.w);
        m[7] = fmaxf(m[7], bfhi(v.w)); sm[7] += bfhi(v.w);
    }
    #pragma unroll
    for (int i = 0; i < 8; ++i) {
        lmx[wave * 512 + lane * 8 + i] = m[i];
        lsm[wave * 512 + lane * 8 + i] = sm[i];
    }
    __syncthreads();
    #pragma unroll
    for (int cc = 0; cc < 2; ++cc) {
        int ch = tid * 2 + cc;
        float mx = fmaxf(fmaxf(lmx[ch], lmx[512 + ch]),
                         fmaxf(lmx[1024 + ch], lmx[1536 + ch]));
        float sv = (lsm[ch] + lsm[512 + ch]) + (lsm[1024 + ch] + lsm[1536 + ch]);
        atomicMax((int*)&pmax[ch], __float_as_int(mx));   // values >= 0
        atomicAdd(&psum[ch], sv);
    }
}

// ---------- prep: cvt x | wt transpose | zero deg/pmax/psum ----------
#define NB_CVT 5000
#define NB_WT  192
#define NB_ZD  79
__global__ __launch_bounds__(256) void prep_k(const float* __restrict__ x,
                                              ushort* __restrict__ xb,
                                              const float* __restrict__ W1,
                                              const float* __restrict__ W2,
                                              const float* __restrict__ W3,
                                              ushort* __restrict__ T1,
                                              ushort* __restrict__ T2,
                                              ushort* __restrict__ T3,
                                              int* __restrict__ deg,
                                              float* __restrict__ pmax,
                                              float* __restrict__ psum) {
    __shared__ float t[64][65];
    const int b = blockIdx.x;
    const int tid = threadIdx.x;
    if (b < NB_CVT) {
        int c = b * 256 + tid;
        const float4* p = (const float4*)x + (size_t)c * 2;
        float4 a = p[0], q = p[1];
        uint4 o;
        o.x = pack2(a.x, a.y); o.y = pack2(a.z, a.w);
        o.z = pack2(q.x, q.y); o.w = pack2(q.z, q.w);
        ((uint4*)xb)[c] = o;
    } else if (b < NB_CVT + NB_WT) {
        int idx = b - NB_CVT;
        int layer = idx >> 6, rem = idx & 63;
        const float* W = (layer == 0) ? W1 : (layer == 1) ? W2 : W3;
        ushort* T      = (layer == 0) ? T1 : (layer == 1) ? T2 : T3;
        int kb = (rem >> 3) * 64, nb = (rem & 7) * 64;
        int c = tid & 63, r4 = tid >> 6;
        #pragma unroll
        for (int l = 0; l < 16; ++l) {
            int r = l * 4 + r4;
            t[r][c] = W[(size_t)(kb + r) * HD + nb + c];
        }
        __syncthreads();
        #pragma unroll
        for (int l = 0; l < 16; ++l) {
            int r = l * 4 + r4;
            T[(size_t)(nb + r) * HD + kb + c] = f2bf(t[c][r]);
        }
    } else if (b < NB_CVT + NB_WT + NB_ZD) {
        int i = (b - NB_CVT - NB_WT) * 256 + tid;
        if (i < N_NODES) deg[i] = 0;
    } else if (b < NB_CVT + NB_WT + NB_ZD + 6) {
        int i = (b - NB_CVT - NB_WT - NB_ZD) * 256 + tid;
        pmax[i] = 0.f;
    } else {
        int i = (b - NB_CVT - NB_WT - NB_ZD - 6) * 256 + tid;
        psum[i] = 0.f;
    }
}

// ---------- fused1: gemm layer1 (0..627) || hist (628..1877) ----------
__global__ __launch_bounds__(256) void fused1_k(const ushort* __restrict__ xb,
                                                const ushort* __restrict__ wt1,
                                                ushort* __restrict__ s,
                                                const int* __restrict__ rows,
                                                int* __restrict__ deg) {
    __shared__ __align__(16) char smem[16384];
    const int b = blockIdx.x;
    if (b < 628) {
        gemm_tile(xb, wt1, s, b, smem);
    } else {
        int e = (b - 628) * 256 + threadIdx.x;   // 1250*256 == N_EDGES exactly
        atomicAdd(&deg[rows[e]], 1);
    }
}

// ---------- scan: one workgroup; prefix sum + degree-sort perm (LDS cursors)-
// r6 post-mortem: perm built in fill_k with GLOBAL bucket atomics -> modal
// degree bucket (~2000 rows) serialized at device-atomic latency, fill_k
// 66us @ VALU 0.1%. Fix: build perm HERE with LDS bucket cursors (same-bank
// LDS atomics ~ cycles, worst bucket ~2000 x few cy ~ 2us). Zero global
// atomic traffic; perm writes are contiguous per bucket.
__global__ __launch_bounds__(1024) void scan_k(const int* __restrict__ deg,
                                               int* __restrict__ rowstart,
                                               int* __restrict__ cursor,
                                               int* __restrict__ perm) {
    __shared__ int wsum[16];
    __shared__ int hist[256];
    __shared__ int boff[256];
    const int tid = threadIdx.x;
    const int lane = tid & 63, wv = tid >> 6;
    if (tid < 256) hist[tid] = 0;
    __syncthreads();
    int carry = 0;
    for (int base = 0; base < N_NODES; base += 1024) {
        int i = base + tid;
        int v = (i < N_NODES) ? deg[i] : 0;
        if (i < N_NODES) atomicAdd(&hist[v < 255 ? v : 255], 1);
        int incl = v;
        #pragma unroll
        for (int off = 1; off < 64; off <<= 1) {
            int t = __shfl_up(incl, off, 64);
            if (lane >= off) incl += t;
        }
        if (lane == 63) wsum[wv] = incl;
        __syncthreads();
        int woff = 0, tot = 0;
        #pragma unroll
        for (int w = 0; w < 16; ++w) {
            int sv = wsum[w];
            if (w < wv) woff += sv;
            tot += sv;
        }
        if (i < N_NODES) {
            int ex = carry + woff + incl - v;
            rowstart[i] = ex;
            cursor[i]   = ex;
        }
        carry += tot;
        __syncthreads();
    }
    if (tid == 0) {
        rowstart[N_NODES] = carry;
        int a = 0;
        for (int d = 0; d < 256; ++d) { boff[d] = a; a += hist[d]; }
    }
    __syncthreads();
    for (int base = 0; base < N_NODES; base += 1024) {
        int i = base + tid;
        if (i < N_NODES) {
            int d = deg[i]; if (d > 255) d = 255;
            int p = atomicAdd(&boff[d], 1);     // LDS cursor: cheap contention
            perm[p] = i;                        // ascending degree order
        }
    }
}

// ---------- fill CSR (edges only; reverted to proven r5 form) ---------------
__global__ void fill_k(const int* __restrict__ rows, const int* __restrict__ cols,
                       const float* __restrict__ vals, int* __restrict__ cursor,
                       int2* __restrict__ csr_cv) {
    int e = blockIdx.x * blockDim.x + threadIdx.x;
    if (e < N_EDGES) {
        int p = atomicAdd(&cursor[rows[e]], 1);
        csr_cv[p] = make_int2(cols[e], __float_as_int(vals[e]));
    }
}

// ---------- aggregate v6: sliced + pinned + pipelined + degree-sorted -------
// (unchanged from r6 agg; this round isolates the fill_k fix so agg's
// counters become visible again)
__device__ inline void fma8(float* acc, uint4 v, float w) {
    acc[0] += w * bflo(v.x); acc[1] += w * bfhi(v.x);
    acc[2] += w * bflo(v.y); acc[3] += w * bfhi(v.y);
    acc[4] += w * bflo(v.z); acc[5] += w * bfhi(v.z);
    acc[6] += w * bflo(v.w); acc[7] += w * bfhi(v.w);
}

#define RPG 2                                    // rows per 8-lane group
#define AGG_RPB (32 * RPG)                       // 64 rows per block
#define AGG_CHUNKS ((N_NODES + AGG_RPB - 1) / AGG_RPB)   // 313
#define AGG_BLOCKS (8 * AGG_CHUNKS)              // 2504

__global__ __launch_bounds__(256) void agg_k(const ushort* __restrict__ s,
                                             const int* __restrict__ rowstart,
                                             const int2* __restrict__ csr_cv,
                                             const int* __restrict__ perm,
                                             const float* __restrict__ bias,
                                             ushort* __restrict__ hout) {
    const int slice = blockIdx.x & 7;            // XCD-pinned channel slice
    const int cidx  = (AGG_CHUNKS - 1) - (int)(blockIdx.x >> 3);  // LPT order
    const int wave = threadIdx.x >> 6, lane = threadIdx.x & 63;
    const int g = lane >> 3, sub = lane & 7;     // group, 16B channel chunk
    const uint4* s4 = (const uint4*)s;
    const size_t sbase = (size_t)slice * 8 + sub;
    uint4* houtp = (uint4*)hout + slice * 8 + sub;
    const float4 b0 = ((const float4*)bias)[slice * 16 + sub * 2];
    const float4 b1 = ((const float4*)bias)[slice * 16 + sub * 2 + 1];
    const int ibase = cidx * AGG_RPB + wave * (8 * RPG) + g * RPG;

    #pragma unroll
    for (int rr = 0; rr < RPG; ++rr) {
        const int idx = ibase + rr;
        int row = 0, beg = 0, end = 0;
        if (idx < N_NODES) {                     // padded tail rows: no work
            row = perm[idx];                     // degree-sorted assignment
            beg = rowstart[row];
            end = rowstart[row + 1];
        }
        float acc[8] = {};
        int j = beg;
        int2 m0, m1, m2, m3;
        if (j < end) {                           // prime the meta pipeline
            m0 = csr_cv[j];
            m1 = csr_cv[(j + 1 < end) ? j + 1 : end - 1];
            m2 = csr_cv[(j + 2 < end) ? j + 2 : end - 1];
            m3 = csr_cv[(j + 3 < end) ? j + 3 : end - 1];
        }
        while (j < end) {
            const int jn = j + 4;
            const int cl = end - 1;
            // prefetch next trip's metadata (clamped; overlaps the gathers)
            int2 n0 = csr_cv[(jn     < end) ? jn     : cl];
            int2 n1 = csr_cv[(jn + 1 < end) ? jn + 1 : cl];
            int2 n2 = csr_cv[(jn + 2 < end) ? jn + 2 : cl];
            int2 n3 = csr_cv[(jn + 3 < end) ? jn + 3 : cl];
            // 4 independent 128B gathers in flight per group
            uint4 v0 = s4[(size_t)m0.x * 64 + sbase];
            uint4 v1 = s4[(size_t)m1.x * 64 + sbase];
            uint4 v2 = s4[(size_t)m2.x * 64 + sbase];
            uint4 v3 = s4[(size_t)m3.x * 64 + sbase];
            float w0 = __int_as_float(m0.y);     // j < end always valid
            float w1 = (j + 1 < end) ? __int_as_float(m1.y) : 0.f;
            float w2 = (j + 2 < end) ? __int_as_float(m2.y) : 0.f;
            float w3 = (j + 3 < end) ? __int_as_float(m3.y) : 0.f;
            fma8(acc, v0, w0);
            fma8(acc, v1, w1);
            fma8(acc, v2, w2);
            fma8(acc, v3, w3);
            m0 = n0; m1 = n1; m2 = n2; m3 = n3;
            j = jn;
        }
        if (idx < N_NODES) {                     // flush row (8 lanes = 128B)
            uint4 ov;
            ov.x = pack2(fmaxf(acc[0] + b0.x, 0.f), fmaxf(acc[1] + b0.y, 0.f));
            ov.y = pack2(fmaxf(acc[2] + b0.z, 0.f), fmaxf(acc[3] + b0.w, 0.f));
            ov.z = pack2(fmaxf(acc[4] + b1.x, 0.f), fmaxf(acc[5] + b1.y, 0.f));
            ov.w = pack2(fmaxf(acc[6] + b1.z, 0.f), fmaxf(acc[7] + b1.w, 0.f));
            houtp[(size_t)row * 64] = ov;
        }
    }
}

// ---------- fused gemm || pool (both read-only on h; proven) ----------
__global__ __launch_bounds__(256) void fusedgp_k(const ushort* __restrict__ h,
                                                 const ushort* __restrict__ wt,
                                                 ushort* __restrict__ s,
                                                 float* __restrict__ pmax,
                                                 float* __restrict__ psum) {
    __shared__ __align__(16) char smem[16384];
    const int b = blockIdx.x;
    if (b < 628) gemm_tile(h, wt, s, b, smem);
    else         pool_part(h, pmax, psum, b - 628, smem);
}

// ---------- standalone pool (layer 3) ----------
__global__ __launch_bounds__(256) void pool_k(const ushort* __restrict__ h,
                                              float* __restrict__ pmax,
                                              float* __restrict__ psum) {
    __shared__ __align__(16) char smem[16384];
    pool_part(h, pmax, psum, blockIdx.x, smem);
}

// ---------- head MLP + log_softmax (1024 threads, split-k; proven) ----------
__global__ __launch_bounds__(1024) void mlp_k(const float* __restrict__ pool_max,
                                              const float* __restrict__ pool_sum,
                                              const float* __restrict__ l1W,
                                              const float* __restrict__ l1b,
                                              const float* __restrict__ l2W,
                                              const float* __restrict__ l2b,
                                              const float* __restrict__ l3W,
                                              const float* __restrict__ l3b,
                                              float* __restrict__ out) {
    __shared__ float g[1024];
    __shared__ float part[1024];
    __shared__ float a1[128];
    __shared__ float a2[64];
    __shared__ float a3[10];
    const int tid = threadIdx.x;
    if (tid < 512) {
        g[tid]       = pool_max[tid] + pool_max[512 + tid] + pool_max[1024 + tid];
        g[512 + tid] = (pool_sum[tid] + pool_sum[512 + tid] + pool_sum[1024 + tid]) *
                       (1.0f / N_NODES);
    }
    __syncthreads();
    {
        int ch = tid & 127, sl = tid >> 7;
        float acc = (sl == 0) ? l1b[ch] : 0.f;
        int k0 = sl * 128;
        #pragma unroll 4
        for (int k = k0; k < k0 + 128; ++k) acc += g[k] * l1W[k * 128 + ch];
        part[tid] = acc;
    }
    __syncthreads();
    if (tid < 128) {
        float a = part[tid];
        #pragma unroll
        for (int ss = 1; ss < 8; ++ss) a += part[tid + ss * 128];
        a1[tid] = fmaxf(a, 0.f);
    }
    __syncthreads();
    if (tid < 512) {
        int ch = tid & 63, sl = tid >> 6;
        float acc = (sl == 0) ? l2b[ch] : 0.f;
        int k0 = sl * 16;
        #pragma unroll
        for (int k = k0; k < k0 + 16; ++k) acc += a1[k] * l2W[k * 64 + ch];
        part[tid] = acc;
    }
    __syncthreads();
    if (tid < 64) {
        float a = part[tid];
        #pragma unroll
        for (int ss = 1; ss < 8; ++ss) a += part[tid + ss * 64];
        a2[tid] = fmaxf(a, 0.f);
    }
    __syncthreads();
    if (tid < 10) {
        float acc = l3b[tid];
        for (int k = 0; k < 64; ++k) acc += a2[k] * l3W[k * 10 + tid];
        a3[tid] = acc;
    }
    __syncthreads();
    if (tid == 0) {
        float m = a3[0];
        for (int j = 1; j < 10; ++j) m = fmaxf(m, a3[j]);
        float ssum = 0.f;
        for (int j = 0; j < 10; ++j) ssum += expf(a3[j] - m);
        float lse = m + logf(ssum);
        for (int j = 0; j < 10; ++j) out[j] = a3[j] - lse;
    }
}

extern "C" void kernel_launch(void* const* d_in, const int* in_sizes, int n_in,
                              void* d_out, int out_size, void* d_ws, size_t ws_size,
                              hipStream_t stream) {
    const float* x    = (const float*)d_in[0];
    const int*   rows = (const int*)  d_in[1];
    const int*   cols = (const int*)  d_in[2];
    const float* vals = (const float*)d_in[3];
    const float* W1   = (const float*)d_in[4];
    const float* b1   = (const float*)d_in[5];
    const float* W2   = (const float*)d_in[6];
    const float* b2   = (const float*)d_in[7];
    const float* W3   = (const float*)d_in[8];
    const float* b3   = (const float*)d_in[9];
    const float* l1W  = (const float*)d_in[10];
    const float* l1b  = (const float*)d_in[11];
    const float* l2W  = (const float*)d_in[12];
    const float* l2b  = (const float*)d_in[13];
    const float* l3W  = (const float*)d_in[14];
    const float* l3b  = (const float*)d_in[15];
    float* out = (float*)d_out;

    char* ws = (char*)d_ws;
    size_t off = 0;
    auto alloc = [&](size_t bytes) {
        void* p = ws + off;
        off += (bytes + 255) & ~(size_t)255;
        return p;
    };
    ushort* xb       = (ushort*)alloc((size_t)N_NODES * HD * 2);
    ushort* s        = (ushort*)alloc((size_t)N_NODES * HD * 2);
    ushort* hb       = (ushort*)alloc((size_t)N_NODES * HD * 2);
    ushort* wt1      = (ushort*)alloc((size_t)HD * HD * 2);
    ushort* wt2      = (ushort*)alloc((size_t)HD * HD * 2);
    ushort* wt3      = (ushort*)alloc((size_t)HD * HD * 2);
    int*    deg      = (int*)   alloc((size_t)N_NODES * 4);
    float*  pmax     = (float*) alloc((size_t)3 * 512 * 4);
    float*  psum     = (float*) alloc((size_t)3 * 512 * 4);
    int*    rowstart = (int*)   alloc((size_t)(N_NODES + 1) * 4);
    int*    cursor   = (int*)   alloc((size_t)N_NODES * 4);
    int2*   csr_cv   = (int2*)  alloc((size_t)N_EDGES * 8);
    int*    perm     = (int*)   alloc((size_t)N_NODES * 4);
    (void)ws_size; (void)in_sizes; (void)n_in; (void)out_size;

    // 1: prep (cvt + wt + zero deg/pmax/psum)
    prep_k<<<NB_CVT + NB_WT + NB_ZD + 12, 256, 0, stream>>>(
        x, xb, W1, W2, W3, wt1, wt2, wt3, deg, pmax, psum);
    // 2: gemm1 || hist
    fused1_k<<<628 + 1250, 256, 0, stream>>>(xb, wt1, s, rows, deg);
    // 3: scan (+ degree-sort perm via LDS cursors)
    scan_k<<<1, 1024, 0, stream>>>(deg, rowstart, cursor, perm);
    // 4: fill CSR (edges only)
    fill_k<<<(N_EDGES + 255) / 256, 256, 0, stream>>>(rows, cols, vals, cursor,
                                                      csr_cv);
    // 5: agg1
    agg_k<<<AGG_BLOCKS, 256, 0, stream>>>(s, rowstart, csr_cv, perm, b1, hb);
    // 6: gemm2 || pool1
    fusedgp_k<<<628 + 256, 256, 0, stream>>>(hb, wt2, s, pmax, psum);
    // 7: agg2
    agg_k<<<AGG_BLOCKS, 256, 0, stream>>>(s, rowstart, csr_cv, perm, b2, hb);
    // 8: gemm3 || pool2
    fusedgp_k<<<628 + 256, 256, 0, stream>>>(hb, wt3, s, pmax + 512, psum + 512);
    // 9: agg3
    agg_k<<<AGG_BLOCKS, 256, 0, stream>>>(s, rowstart, csr_cv, perm, b3, hb);
    // 10: pool3
    pool_k<<<256, 256, 0, stream>>>(hb, pmax + 1024, psum + 1024);
    // 11: mlp head
    mlp_k<<<1, 1024, 0, stream>>>(pmax, psum, l1W, l1b, l2W, l2b, l3W, l3b, out);
}

// Round 8
// 378.264 us; speedup vs baseline: 1.1097x; 1.0089x over previous
//
#include <hip/hip_runtime.h>
#include <hip/hip_bf16.h>

#define N_NODES 20000
#define N_EDGES 320000
#define HD 512

typedef __attribute__((ext_vector_type(8))) short bf16x8;
typedef __attribute__((ext_vector_type(4))) float f32x4;

// ---------- bf16 helpers ----------
__device__ inline ushort f2bf(float f) {
    uint u = __float_as_uint(f);
    uint r = (u + 0x7fffu + ((u >> 16) & 1u)) >> 16;
    return (ushort)r;
}
__device__ inline uint pack2(float a, float b) {
    return (uint)f2bf(a) | ((uint)f2bf(b) << 16);
}
__device__ inline float bflo(uint u) { return __uint_as_float(u << 16); }
__device__ inline float bfhi(uint u) { return __uint_as_float(u & 0xffff0000u); }

__device__ __forceinline__ void async_load16(const void* g, void* l) {
    __builtin_amdgcn_global_load_lds(
        (const __attribute__((address_space(1))) uint*)g,
        (__attribute__((address_space(3))) uint*)l,
        16, 0, 0);
}

// ---------- gemm tile: 128x128, global_load_lds, XOR swizzle (proven) -------
// remap != nullptr: C-row gr is stored at row remap[gr] (row-level 1KB
// scatter; used by gemm1 to emit s directly in degree-sorted node order).
__device__ __forceinline__ void gemm_tile(const ushort* __restrict__ A,
                                          const ushort* __restrict__ Bt,
                                          ushort* __restrict__ C,
                                          const int* __restrict__ remap,
                                          int tile, char* smem) {
    short* As = (short*)smem;
    short* Bs = (short*)(smem + 128 * 32 * 2);
    const int tid = threadIdx.x;
    const int lane = tid & 63;
    const int wave = tid >> 6;
    const int l15 = lane & 15;
    const int q = lane >> 4;
    const int wrow = wave >> 1, wcol = wave & 1;
    const int row0 = (tile >> 2) * 128;
    const int col0 = (tile & 3) * 128;

    const int srow = lane >> 2;
    const int kc   = (lane & 3) ^ ((lane >> 3) & 3);
    const int sl   = (l15 >> 1) & 3;

    f32x4 acc[4][4] = {};

    for (int k0 = 0; k0 < HD; k0 += 32) {
        #pragma unroll
        for (int l = 0; l < 2; ++l) {
            const int rbase = wave * 32 + l * 16;
            const ushort* ga = &A [(size_t)(row0 + rbase + srow) * HD + k0 + kc * 8];
            const ushort* gb = &Bt[(size_t)(col0 + rbase + srow) * HD + k0 + kc * 8];
            async_load16(ga, &As[rbase * 32]);
            async_load16(gb, &Bs[rbase * 32]);
        }
        __syncthreads();
        bf16x8 aF[4], bF[4];
        #pragma unroll
        for (int i = 0; i < 4; ++i)
            aF[i] = *(bf16x8*)&As[(wrow * 64 + i * 16 + l15) * 32 + (q ^ sl) * 8];
        #pragma unroll
        for (int j = 0; j < 4; ++j)
            bF[j] = *(bf16x8*)&Bs[(wcol * 64 + j * 16 + l15) * 32 + (q ^ sl) * 8];
        #pragma unroll
        for (int i = 0; i < 4; ++i)
            #pragma unroll
            for (int j = 0; j < 4; ++j)
                acc[i][j] = __builtin_amdgcn_mfma_f32_16x16x32_bf16(aF[i], bF[j], acc[i][j], 0, 0, 0);
        __syncthreads();
    }
    #pragma unroll
    for (int i = 0; i < 4; ++i) {
        #pragma unroll
        for (int r = 0; r < 4; ++r) {
            int gr = row0 + wrow * 64 + i * 16 + q * 4 + r;
            if (gr < N_NODES) {
                int orow = remap ? remap[gr] : gr;
                #pragma unroll
                for (int j = 0; j < 4; ++j) {
                    int gc = col0 + wcol * 64 + j * 16 + l15;
                    C[(size_t)orow * HD + gc] = f2bf(acc[i][j][r]);
                }
            }
        }
    }
}

// ---------- pool partial (proven; order-invariant over rows) ----------
__device__ __forceinline__ void pool_part(const ushort* __restrict__ h,
                                          float* __restrict__ pmax,
                                          float* __restrict__ psum,
                                          int pb, char* smem) {
    float* lmx = (float*)smem;           // 2048 floats
    float* lsm = lmx + 2048;             // 2048 floats
    const int tid = threadIdx.x;
    const int wave = tid >> 6, lane = tid & 63;
    const uint4* h4 = (const uint4*)h;
    float m[8] = {}, sm[8] = {};
    for (int r = pb * 4 + wave; r < N_NODES; r += 1024) {
        uint4 v = h4[(size_t)r * 64 + lane];
        m[0] = fmaxf(m[0], bflo(v.x)); sm[0] += bflo(v.x);
        m[1] = fmaxf(m[1], bfhi(v.x)); sm[1] += bfhi(v.x);
        m[2] = fmaxf(m[2], bflo(v.y)); sm[2] += bflo(v.y);
        m[3] = fmaxf(m[3], bfhi(v.y)); sm[3] += bfhi(v.y);
        m[4] = fmaxf(m[4], bflo(v.z)); sm[4] += bflo(v.z);
        m[5] = fmaxf(m[5], bfhi(v.z)); sm[5] += bfhi(v.z);
        m[6] = fmaxf(m[6], bflo(v.w)); sm[6] += bflo(v.w);
        m[7] = fmaxf(m[7], bfhi(v.w)); sm[7] += bfhi(v.w);
    }
    #pragma unroll
    for (int i = 0; i < 8; ++i) {
        lmx[wave * 512 + lane * 8 + i] = m[i];
        lsm[wave * 512 + lane * 8 + i] = sm[i];
    }
    __syncthreads();
    #pragma unroll
    for (int cc = 0; cc < 2; ++cc) {
        int ch = tid * 2 + cc;
        float mx = fmaxf(fmaxf(lmx[ch], lmx[512 + ch]),
                         fmaxf(lmx[1024 + ch], lmx[1536 + ch]));
        float sv = (lsm[ch] + lsm[512 + ch]) + (lsm[1024 + ch] + lsm[1536 + ch]);
        atomicMax((int*)&pmax[ch], __float_as_int(mx));   // values >= 0
        atomicAdd(&psum[ch], sv);
    }
}

// ---------- prep: cvt x | wt transpose | zero deg/pmax/psum ----------
#define NB_CVT 5000
#define NB_WT  192
#define NB_ZD  79
__global__ __launch_bounds__(256) void prep_k(const float* __restrict__ x,
                                              ushort* __restrict__ xb,
                                              const float* __restrict__ W1,
                                              const float* __restrict__ W2,
                                              const float* __restrict__ W3,
                                              ushort* __restrict__ T1,
                                              ushort* __restrict__ T2,
                                              ushort* __restrict__ T3,
                                              int* __restrict__ deg,
                                              float* __restrict__ pmax,
                                              float* __restrict__ psum) {
    __shared__ float t[64][65];
    const int b = blockIdx.x;
    const int tid = threadIdx.x;
    if (b < NB_CVT) {
        int c = b * 256 + tid;
        const float4* p = (const float4*)x + (size_t)c * 2;
        float4 a = p[0], q = p[1];
        uint4 o;
        o.x = pack2(a.x, a.y); o.y = pack2(a.z, a.w);
        o.z = pack2(q.x, q.y); o.w = pack2(q.z, q.w);
        ((uint4*)xb)[c] = o;
    } else if (b < NB_CVT + NB_WT) {
        int idx = b - NB_CVT;
        int layer = idx >> 6, rem = idx & 63;
        const float* W = (layer == 0) ? W1 : (layer == 1) ? W2 : W3;
        ushort* T      = (layer == 0) ? T1 : (layer == 1) ? T2 : T3;
        int kb = (rem >> 3) * 64, nb = (rem & 7) * 64;
        int c = tid & 63, r4 = tid >> 6;
        #pragma unroll
        for (int l = 0; l < 16; ++l) {
            int r = l * 4 + r4;
            t[r][c] = W[(size_t)(kb + r) * HD + nb + c];
        }
        __syncthreads();
        #pragma unroll
        for (int l = 0; l < 16; ++l) {
            int r = l * 4 + r4;
            T[(size_t)(nb + r) * HD + kb + c] = f2bf(t[c][r]);
        }
    } else if (b < NB_CVT + NB_WT + NB_ZD) {
        int i = (b - NB_CVT - NB_WT) * 256 + tid;
        if (i < N_NODES) deg[i] = 0;
    } else if (b < NB_CVT + NB_WT + NB_ZD + 6) {
        int i = (b - NB_CVT - NB_WT - NB_ZD) * 256 + tid;
        pmax[i] = 0.f;
    } else {
        int i = (b - NB_CVT - NB_WT - NB_ZD - 6) * 256 + tid;
        psum[i] = 0.f;
    }
}

// ---------- hist: degree histogram (must follow prep's deg zeroing) ---------
__global__ __launch_bounds__(256) void hist_k(const int* __restrict__ rows,
                                              int* __restrict__ deg) {
    int e = blockIdx.x * 256 + threadIdx.x;      // 1250*256 == N_EDGES exactly
    atomicAdd(&deg[rows[e]], 1);
}

// ---------- scan: degree-sort relabeling, one workgroup ---------------------
// Builds: inv[orig row] = sorted position p (ascending degree), and the
// CSR rowstart/cursor in SORTED space, computed analytically from the
// degree histogram (bucket d occupies rows [boff0[d],boff0[d+1]) and edges
// [ebase[d]...], each row exactly d edges) -- no perm array needed.
// LDS bucket cursors for the scatter (r7-proven: contention ~cycles).
__global__ __launch_bounds__(1024) void scan_k(const int* __restrict__ deg,
                                               int* __restrict__ rowstart,
                                               int* __restrict__ cursor,
                                               int* __restrict__ inv) {
    __shared__ int hist[256];
    __shared__ int boff0[256];
    __shared__ int bcur[256];
    __shared__ int ebase[256];
    const int tid = threadIdx.x;
    if (tid < 256) hist[tid] = 0;
    __syncthreads();
    for (int base = 0; base < N_NODES; base += 1024) {   // pass 1: histogram
        int i = base + tid;
        if (i < N_NODES) {
            int d = deg[i]; if (d > 255) d = 255;
            atomicAdd(&hist[d], 1);
        }
    }
    __syncthreads();
    if (tid == 0) {
        int a = 0, e = 0;
        for (int d = 0; d < 256; ++d) {
            boff0[d] = a; bcur[d] = a; ebase[d] = e;
            a += hist[d]; e += hist[d] * d;
        }
    }
    __syncthreads();
    for (int base = 0; base < N_NODES; base += 1024) {   // pass 2: inv scatter
        int i = base + tid;
        if (i < N_NODES) {
            int d = deg[i]; if (d > 255) d = 255;
            int p = atomicAdd(&bcur[d], 1);
            inv[i] = p;
        }
    }
    __syncthreads();
    for (int base = 0; base < N_NODES; base += 1024) {   // pass 3: rowstart
        int p = base + tid;
        if (p < N_NODES) {
            int d = 0;                                    // max d: boff0[d]<=p
            #pragma unroll
            for (int step = 128; step; step >>= 1)
                if (d + step < 256 && boff0[d + step] <= p) d += step;
            int rs = ebase[d] + (p - boff0[d]) * d;
            rowstart[p] = rs;
            cursor[p]   = rs;
        }
    }
    if (tid == 0) rowstart[N_NODES] = N_EDGES;
}

// ---------- gemm1 (inv-scatter epilogue) || fill CSR (translated) -----------
__global__ __launch_bounds__(256) void gf1_k(const ushort* __restrict__ xb,
                                             const ushort* __restrict__ wt1,
                                             ushort* __restrict__ s,
                                             const int* __restrict__ rows,
                                             const int* __restrict__ cols,
                                             const float* __restrict__ vals,
                                             const int* __restrict__ inv,
                                             int* __restrict__ cursor,
                                             int2* __restrict__ csr_cv) {
    __shared__ __align__(16) char smem[16384];
    const int b = blockIdx.x;
    if (b < 628) {
        gemm_tile(xb, wt1, s, inv, b, smem);     // s lands in sorted order
    } else {
        int e = (b - 628) * 256 + threadIdx.x;   // 1250*256 == N_EDGES exactly
        int rp = inv[rows[e]];                   // sorted row id
        int cp = inv[cols[e]];                   // sorted col id (s is sorted)
        int p = atomicAdd(&cursor[rp], 1);
        csr_cv[p] = make_int2(cp, __float_as_int(vals[e]));
    }
}

// ---------- aggregate v8: sorted node space -> contiguous + balanced --------
// r7 post-mortem: sorting only the ASSIGNMENT scattered rowstart/meta/hout
// accesses (random row ids per wave) -- balance gain eaten by locality loss.
// Now the node space itself is degree-sorted: row == idx. A wave's 16 rows
// are consecutive AND equal-degree (lockstep waste ~0); metadata is one
// contiguous stream; hout writes contiguous. LPT via reversed cidx (heaviest
// chunks first). Gather pipeline (4-deep, branchless) unchanged (proven).
__device__ inline void fma8(float* acc, uint4 v, float w) {
    acc[0] += w * bflo(v.x); acc[1] += w * bfhi(v.x);
    acc[2] += w * bflo(v.y); acc[3] += w * bfhi(v.y);
    acc[4] += w * bflo(v.z); acc[5] += w * bfhi(v.z);
    acc[6] += w * bflo(v.w); acc[7] += w * bfhi(v.w);
}

#define RPG 2                                    // rows per 8-lane group
#define AGG_RPB (32 * RPG)                       // 64 rows per block
#define AGG_CHUNKS ((N_NODES + AGG_RPB - 1) / AGG_RPB)   // 313
#define AGG_BLOCKS (8 * AGG_CHUNKS)              // 2504

__global__ __launch_bounds__(256) void agg_k(const ushort* __restrict__ s,
                                             const int* __restrict__ rowstart,
                                             const int2* __restrict__ csr_cv,
                                             const float* __restrict__ bias,
                                             ushort* __restrict__ hout) {
    const int slice = blockIdx.x & 7;            // XCD-pinned channel slice
    const int cidx  = (AGG_CHUNKS - 1) - (int)(blockIdx.x >> 3);  // LPT order
    const int wave = threadIdx.x >> 6, lane = threadIdx.x & 63;
    const int g = lane >> 3, sub = lane & 7;     // group, 16B channel chunk
    const uint4* s4 = (const uint4*)s;
    const size_t sbase = (size_t)slice * 8 + sub;
    uint4* houtp = (uint4*)hout + slice * 8 + sub;
    const float4 b0 = ((const float4*)bias)[slice * 16 + sub * 2];
    const float4 b1 = ((const float4*)bias)[slice * 16 + sub * 2 + 1];
    const int ibase = cidx * AGG_RPB + wave * (8 * RPG) + g * RPG;

    #pragma unroll
    for (int rr = 0; rr < RPG; ++rr) {
        const int idx = ibase + rr;              // == row (sorted space)
        int beg = 0, end = 0;
        if (idx < N_NODES) {                     // padded tail rows: no work
            beg = rowstart[idx];
            end = rowstart[idx + 1];
        }
        float acc[8] = {};
        int j = beg;
        int2 m0, m1, m2, m3;
        if (j < end) {                           // prime the meta pipeline
            m0 = csr_cv[j];
            m1 = csr_cv[(j + 1 < end) ? j + 1 : end - 1];
            m2 = csr_cv[(j + 2 < end) ? j + 2 : end - 1];
            m3 = csr_cv[(j + 3 < end) ? j + 3 : end - 1];
        }
        while (j < end) {
            const int jn = j + 4;
            const int cl = end - 1;
            // prefetch next trip's metadata (clamped; overlaps the gathers)
            int2 n0 = csr_cv[(jn     < end) ? jn     : cl];
            int2 n1 = csr_cv[(jn + 1 < end) ? jn + 1 : cl];
            int2 n2 = csr_cv[(jn + 2 < end) ? jn + 2 : cl];
            int2 n3 = csr_cv[(jn + 3 < end) ? jn + 3 : cl];
            // 4 independent 128B gathers in flight per group
            uint4 v0 = s4[(size_t)m0.x * 64 + sbase];
            uint4 v1 = s4[(size_t)m1.x * 64 + sbase];
            uint4 v2 = s4[(size_t)m2.x * 64 + sbase];
            uint4 v3 = s4[(size_t)m3.x * 64 + sbase];
            float w0 = __int_as_float(m0.y);     // j < end always valid
            float w1 = (j + 1 < end) ? __int_as_float(m1.y) : 0.f;
            float w2 = (j + 2 < end) ? __int_as_float(m2.y) : 0.f;
            float w3 = (j + 3 < end) ? __int_as_float(m3.y) : 0.f;
            fma8(acc, v0, w0);
            fma8(acc, v1, w1);
            fma8(acc, v2, w2);
            fma8(acc, v3, w3);
            m0 = n0; m1 = n1; m2 = n2; m3 = n3;
            j = jn;
        }
        if (idx < N_NODES) {                     // flush row (8 lanes = 128B)
            uint4 ov;
            ov.x = pack2(fmaxf(acc[0] + b0.x, 0.f), fmaxf(acc[1] + b0.y, 0.f));
            ov.y = pack2(fmaxf(acc[2] + b0.z, 0.f), fmaxf(acc[3] + b0.w, 0.f));
            ov.z = pack2(fmaxf(acc[4] + b1.x, 0.f), fmaxf(acc[5] + b1.y, 0.f));
            ov.w = pack2(fmaxf(acc[6] + b1.z, 0.f), fmaxf(acc[7] + b1.w, 0.f));
            houtp[(size_t)idx * 64] = ov;
        }
    }
}

// ---------- fused gemm || pool (both read-only on h; proven) ----------
__global__ __launch_bounds__(256) void fusedgp_k(const ushort* __restrict__ h,
                                                 const ushort* __restrict__ wt,
                                                 ushort* __restrict__ s,
                                                 float* __restrict__ pmax,
                                                 float* __restrict__ psum) {
    __shared__ __align__(16) char smem[16384];
    const int b = blockIdx.x;
    if (b < 628) gemm_tile(h, wt, s, nullptr, b, smem);
    else         pool_part(h, pmax, psum, b - 628, smem);
}

// ---------- standalone pool (layer 3) ----------
__global__ __launch_bounds__(256) void pool_k(const ushort* __restrict__ h,
                                              float* __restrict__ pmax,
                                              float* __restrict__ psum) {
    __shared__ __align__(16) char smem[16384];
    pool_part(h, pmax, psum, blockIdx.x, smem);
}

// ---------- head MLP + log_softmax (1024 threads, split-k; proven) ----------
__global__ __launch_bounds__(1024) void mlp_k(const float* __restrict__ pool_max,
                                              const float* __restrict__ pool_sum,
                                              const float* __restrict__ l1W,
                                              const float* __restrict__ l1b,
                                              const float* __restrict__ l2W,
                                              const float* __restrict__ l2b,
                                              const float* __restrict__ l3W,
                                              const float* __restrict__ l3b,
                                              float* __restrict__ out) {
    __shared__ float g[1024];
    __shared__ float part[1024];
    __shared__ float a1[128];
    __shared__ float a2[64];
    __shared__ float a3[10];
    const int tid = threadIdx.x;
    if (tid < 512) {
        g[tid]       = pool_max[tid] + pool_max[512 + tid] + pool_max[1024 + tid];
        g[512 + tid] = (pool_sum[tid] + pool_sum[512 + tid] + pool_sum[1024 + tid]) *
                       (1.0f / N_NODES);
    }
    __syncthreads();
    {
        int ch = tid & 127, sl = tid >> 7;
        float acc = (sl == 0) ? l1b[ch] : 0.f;
        int k0 = sl * 128;
        #pragma unroll 4
        for (int k = k0; k < k0 + 128; ++k) acc += g[k] * l1W[k * 128 + ch];
        part[tid] = acc;
    }
    __syncthreads();
    if (tid < 128) {
        float a = part[tid];
        #pragma unroll
        for (int ss = 1; ss < 8; ++ss) a += part[tid + ss * 128];
        a1[tid] = fmaxf(a, 0.f);
    }
    __syncthreads();
    if (tid < 512) {
        int ch = tid & 63, sl = tid >> 6;
        float acc = (sl == 0) ? l2b[ch] : 0.f;
        int k0 = sl * 16;
        #pragma unroll
        for (int k = k0; k < k0 + 16; ++k) acc += a1[k] * l2W[k * 64 + ch];
        part[tid] = acc;
    }
    __syncthreads();
    if (tid < 64) {
        float a = part[tid];
        #pragma unroll
        for (int ss = 1; ss < 8; ++ss) a += part[tid + ss * 64];
        a2[tid] = fmaxf(a, 0.f);
    }
    __syncthreads();
    if (tid < 10) {
        float acc = l3b[tid];
        for (int k = 0; k < 64; ++k) acc += a2[k] * l3W[k * 10 + tid];
        a3[tid] = acc;
    }
    __syncthreads();
    if (tid == 0) {
        float m = a3[0];
        for (int j = 1; j < 10; ++j) m = fmaxf(m, a3[j]);
        float ssum = 0.f;
        for (int j = 0; j < 10; ++j) ssum += expf(a3[j] - m);
        float lse = m + logf(ssum);
        for (int j = 0; j < 10; ++j) out[j] = a3[j] - lse;
    }
}

extern "C" void kernel_launch(void* const* d_in, const int* in_sizes, int n_in,
                              void* d_out, int out_size, void* d_ws, size_t ws_size,
                              hipStream_t stream) {
    const float* x    = (const float*)d_in[0];
    const int*   rows = (const int*)  d_in[1];
    const int*   cols = (const int*)  d_in[2];
    const float* vals = (const float*)d_in[3];
    const float* W1   = (const float*)d_in[4];
    const float* b1   = (const float*)d_in[5];
    const float* W2   = (const float*)d_in[6];
    const float* b2   = (const float*)d_in[7];
    const float* W3   = (const float*)d_in[8];
    const float* b3   = (const float*)d_in[9];
    const float* l1W  = (const float*)d_in[10];
    const float* l1b  = (const float*)d_in[11];
    const float* l2W  = (const float*)d_in[12];
    const float* l2b  = (const float*)d_in[13];
    const float* l3W  = (const float*)d_in[14];
    const float* l3b  = (const float*)d_in[15];
    float* out = (float*)d_out;

    char* ws = (char*)d_ws;
    size_t off = 0;
    auto alloc = [&](size_t bytes) {
        void* p = ws + off;
        off += (bytes + 255) & ~(size_t)255;
        return p;
    };
    ushort* xb       = (ushort*)alloc((size_t)N_NODES * HD * 2);
    ushort* s        = (ushort*)alloc((size_t)N_NODES * HD * 2);
    ushort* hb       = (ushort*)alloc((size_t)N_NODES * HD * 2);
    ushort* wt1      = (ushort*)alloc((size_t)HD * HD * 2);
    ushort* wt2      = (ushort*)alloc((size_t)HD * HD * 2);
    ushort* wt3      = (ushort*)alloc((size_t)HD * HD * 2);
    int*    deg      = (int*)   alloc((size_t)N_NODES * 4);
    float*  pmax     = (float*) alloc((size_t)3 * 512 * 4);
    float*  psum     = (float*) alloc((size_t)3 * 512 * 4);
    int*    rowstart = (int*)   alloc((size_t)(N_NODES + 1) * 4);
    int*    cursor   = (int*)   alloc((size_t)N_NODES * 4);
    int2*   csr_cv   = (int2*)  alloc((size_t)N_EDGES * 8);
    int*    inv      = (int*)   alloc((size_t)N_NODES * 4);
    (void)ws_size; (void)in_sizes; (void)n_in; (void)out_size;

    // 1: prep (cvt + wt + zero deg/pmax/psum)
    prep_k<<<NB_CVT + NB_WT + NB_ZD + 12, 256, 0, stream>>>(
        x, xb, W1, W2, W3, wt1, wt2, wt3, deg, pmax, psum);
    // 2: degree histogram
    hist_k<<<1250, 256, 0, stream>>>(rows, deg);
    // 3: degree-sort relabeling (inv) + sorted-space CSR offsets
    scan_k<<<1, 1024, 0, stream>>>(deg, rowstart, cursor, inv);
    // 4: gemm1 (scatter to sorted order) || fill CSR (translated)
    gf1_k<<<628 + 1250, 256, 0, stream>>>(xb, wt1, s, rows, cols, vals, inv,
                                          cursor, csr_cv);
    // 5: agg1
    agg_k<<<AGG_BLOCKS, 256, 0, stream>>>(s, rowstart, csr_cv, b1, hb);
    // 6: gemm2 || pool1
    fusedgp_k<<<628 + 256, 256, 0, stream>>>(hb, wt2, s, pmax, psum);
    // 7: agg2
    agg_k<<<AGG_BLOCKS, 256, 0, stream>>>(s, rowstart, csr_cv, b2, hb);
    // 8: gemm3 || pool2
    fusedgp_k<<<628 + 256, 256, 0, stream>>>(hb, wt3, s, pmax + 512, psum + 512);
    // 9: agg3
    agg_k<<<AGG_BLOCKS, 256, 0, stream>>>(s, rowstart, csr_cv, b3, hb);
    // 10: pool3
    pool_k<<<256, 256, 0, stream>>>(hb, pmax + 1024, psum + 1024);
    // 11: mlp head
    mlp_k<<<1, 1024, 0, stream>>>(pmax, psum, l1W, l1b, l2W, l2b, l3W, l3b, out);
}

// Round 9
// 330.442 us; speedup vs baseline: 1.2703x; 1.1447x over previous
//
#include <hip/hip_runtime.h>
#include <hip/hip_bf16.h>

#define N_NODES 20000
#define N_EDGES 320000
#define HD 512

typedef __attribute__((ext_vector_type(8))) short bf16x8;
typedef __attribute__((ext_vector_type(4))) float f32x4;

// ---------- bf16 helpers ----------
__device__ inline ushort f2bf(float f) {
    uint u = __float_as_uint(f);
    uint r = (u + 0x7fffu + ((u >> 16) & 1u)) >> 16;
    return (ushort)r;
}
__device__ inline uint pack2(float a, float b) {
    return (uint)f2bf(a) | ((uint)f2bf(b) << 16);
}
__device__ inline float bflo(uint u) { return __uint_as_float(u << 16); }
__device__ inline float bfhi(uint u) { return __uint_as_float(u & 0xffff0000u); }

__device__ __forceinline__ void async_load16(const void* g, void* l) {
    __builtin_amdgcn_global_load_lds(
        (const __attribute__((address_space(1))) uint*)g,
        (__attribute__((address_space(3))) uint*)l,
        16, 0, 0);
}

// ---------- gemm tile: 128x128, global_load_lds, XOR swizzle (proven) -------
// remap != nullptr: C-row gr is stored at row remap[gr] (row-level 1KB
// scatter; used by gemm1 to emit s directly in degree-sorted node order).
__device__ __forceinline__ void gemm_tile(const ushort* __restrict__ A,
                                          const ushort* __restrict__ Bt,
                                          ushort* __restrict__ C,
                                          const int* __restrict__ remap,
                                          int tile, char* smem) {
    short* As = (short*)smem;
    short* Bs = (short*)(smem + 128 * 32 * 2);
    const int tid = threadIdx.x;
    const int lane = tid & 63;
    const int wave = tid >> 6;
    const int l15 = lane & 15;
    const int q = lane >> 4;
    const int wrow = wave >> 1, wcol = wave & 1;
    const int row0 = (tile >> 2) * 128;
    const int col0 = (tile & 3) * 128;

    const int srow = lane >> 2;
    const int kc   = (lane & 3) ^ ((lane >> 3) & 3);
    const int sl   = (l15 >> 1) & 3;

    f32x4 acc[4][4] = {};

    for (int k0 = 0; k0 < HD; k0 += 32) {
        #pragma unroll
        for (int l = 0; l < 2; ++l) {
            const int rbase = wave * 32 + l * 16;
            const ushort* ga = &A [(size_t)(row0 + rbase + srow) * HD + k0 + kc * 8];
            const ushort* gb = &Bt[(size_t)(col0 + rbase + srow) * HD + k0 + kc * 8];
            async_load16(ga, &As[rbase * 32]);
            async_load16(gb, &Bs[rbase * 32]);
        }
        __syncthreads();
        bf16x8 aF[4], bF[4];
        #pragma unroll
        for (int i = 0; i < 4; ++i)
            aF[i] = *(bf16x8*)&As[(wrow * 64 + i * 16 + l15) * 32 + (q ^ sl) * 8];
        #pragma unroll
        for (int j = 0; j < 4; ++j)
            bF[j] = *(bf16x8*)&Bs[(wcol * 64 + j * 16 + l15) * 32 + (q ^ sl) * 8];
        #pragma unroll
        for (int i = 0; i < 4; ++i)
            #pragma unroll
            for (int j = 0; j < 4; ++j)
                acc[i][j] = __builtin_amdgcn_mfma_f32_16x16x32_bf16(aF[i], bF[j], acc[i][j], 0, 0, 0);
        __syncthreads();
    }
    #pragma unroll
    for (int i = 0; i < 4; ++i) {
        #pragma unroll
        for (int r = 0; r < 4; ++r) {
            int gr = row0 + wrow * 64 + i * 16 + q * 4 + r;
            if (gr < N_NODES) {
                int orow = remap ? remap[gr] : gr;
                #pragma unroll
                for (int j = 0; j < 4; ++j) {
                    int gc = col0 + wcol * 64 + j * 16 + l15;
                    C[(size_t)orow * HD + gc] = f2bf(acc[i][j][r]);
                }
            }
        }
    }
}

// ---------- prep: cvt x | wt transpose | edge histogram -----------------
// deg/pmax/psum are zeroed by one hipMemsetAsync BEFORE this launch, so the
// histogram blocks can run here (no cross-block ordering needed). The
// standalone hist_k dispatch is eliminated; hist overlaps the cvt blocks.
#define NB_CVT 5000
#define NB_WT  192
#define NB_HIST 1250
__global__ __launch_bounds__(256) void prep_k(const float* __restrict__ x,
                                              ushort* __restrict__ xb,
                                              const float* __restrict__ W1,
                                              const float* __restrict__ W2,
                                              const float* __restrict__ W3,
                                              ushort* __restrict__ T1,
                                              ushort* __restrict__ T2,
                                              ushort* __restrict__ T3,
                                              const int* __restrict__ rows,
                                              int* __restrict__ deg) {
    __shared__ float t[64][65];
    const int b = blockIdx.x;
    const int tid = threadIdx.x;
    if (b < NB_CVT) {
        int c = b * 256 + tid;
        const float4* p = (const float4*)x + (size_t)c * 2;
        float4 a = p[0], q = p[1];
        uint4 o;
        o.x = pack2(a.x, a.y); o.y = pack2(a.z, a.w);
        o.z = pack2(q.x, q.y); o.w = pack2(q.z, q.w);
        ((uint4*)xb)[c] = o;
    } else if (b < NB_CVT + NB_WT) {
        int idx = b - NB_CVT;
        int layer = idx >> 6, rem = idx & 63;
        const float* W = (layer == 0) ? W1 : (layer == 1) ? W2 : W3;
        ushort* T      = (layer == 0) ? T1 : (layer == 1) ? T2 : T3;
        int kb = (rem >> 3) * 64, nb = (rem & 7) * 64;
        int c = tid & 63, r4 = tid >> 6;
        #pragma unroll
        for (int l = 0; l < 16; ++l) {
            int r = l * 4 + r4;
            t[r][c] = W[(size_t)(kb + r) * HD + nb + c];
        }
        __syncthreads();
        #pragma unroll
        for (int l = 0; l < 16; ++l) {
            int r = l * 4 + r4;
            T[(size_t)(nb + r) * HD + kb + c] = f2bf(t[c][r]);
        }
    } else {
        int e = (b - NB_CVT - NB_WT) * 256 + tid;  // 1250*256 == N_EDGES
        atomicAdd(&deg[rows[e]], 1);
    }
}

// ---------- scan: degree-sort relabeling, one workgroup (proven r8) ---------
__global__ __launch_bounds__(1024) void scan_k(const int* __restrict__ deg,
                                               int* __restrict__ rowstart,
                                               int* __restrict__ cursor,
                                               int* __restrict__ inv) {
    __shared__ int hist[256];
    __shared__ int boff0[256];
    __shared__ int bcur[256];
    __shared__ int ebase[256];
    const int tid = threadIdx.x;
    if (tid < 256) hist[tid] = 0;
    __syncthreads();
    for (int base = 0; base < N_NODES; base += 1024) {   // pass 1: histogram
        int i = base + tid;
        if (i < N_NODES) {
            int d = deg[i]; if (d > 255) d = 255;
            atomicAdd(&hist[d], 1);
        }
    }
    __syncthreads();
    if (tid == 0) {
        int a = 0, e = 0;
        for (int d = 0; d < 256; ++d) {
            boff0[d] = a; bcur[d] = a; ebase[d] = e;
            a += hist[d]; e += hist[d] * d;
        }
    }
    __syncthreads();
    for (int base = 0; base < N_NODES; base += 1024) {   // pass 2: inv scatter
        int i = base + tid;
        if (i < N_NODES) {
            int d = deg[i]; if (d > 255) d = 255;
            int p = atomicAdd(&bcur[d], 1);
            inv[i] = p;
        }
    }
    __syncthreads();
    for (int base = 0; base < N_NODES; base += 1024) {   // pass 3: rowstart
        int p = base + tid;
        if (p < N_NODES) {
            int d = 0;                                    // max d: boff0[d]<=p
            #pragma unroll
            for (int step = 128; step; step >>= 1)
                if (d + step < 256 && boff0[d + step] <= p) d += step;
            int rs = ebase[d] + (p - boff0[d]) * d;
            rowstart[p] = rs;
            cursor[p]   = rs;
        }
    }
    if (tid == 0) rowstart[N_NODES] = N_EDGES;
}

// ---------- gemm1 (inv-scatter epilogue) || fill CSR (translated) -----------
__global__ __launch_bounds__(256) void gf1_k(const ushort* __restrict__ xb,
                                             const ushort* __restrict__ wt1,
                                             ushort* __restrict__ s,
                                             const int* __restrict__ rows,
                                             const int* __restrict__ cols,
                                             const float* __restrict__ vals,
                                             const int* __restrict__ inv,
                                             int* __restrict__ cursor,
                                             int2* __restrict__ csr_cv) {
    __shared__ __align__(16) char smem[16384];
    const int b = blockIdx.x;
    if (b < 628) {
        gemm_tile(xb, wt1, s, inv, b, smem);     // s lands in sorted order
    } else {
        int e = (b - 628) * 256 + threadIdx.x;   // 1250*256 == N_EDGES exactly
        int rp = inv[rows[e]];                   // sorted row id
        int cp = inv[cols[e]];                   // sorted col id (s is sorted)
        int p = atomicAdd(&cursor[rp], 1);
        csr_cv[p] = make_int2(cp, __float_as_int(vals[e]));
    }
}

// ---------- aggregate v9: sorted space + FUSED max/mean pool epilogue -------
// r8 post-mortem: agg-side optimization exhausted (r5..r8 within 3us); the
// remaining budget is whole dispatches + their traffic. Pool is fused HERE:
// at row flush each lane holds the relu'd slice values -> keep running
// max/sum across its rows, then 3x shfl_xor group-reduce + 2KB LDS cross-wave
// reduce + 128 global atomics per block. This deletes: pool blocks in the
// gemm dispatches, the standalone pool3 (20MB read), and agg3's 20MB hb
// write (hout=nullptr). Gather pipeline + LPT + slicing unchanged (proven).
__device__ inline void fma8(float* acc, uint4 v, float w) {
    acc[0] += w * bflo(v.x); acc[1] += w * bfhi(v.x);
    acc[2] += w * bflo(v.y); acc[3] += w * bfhi(v.y);
    acc[4] += w * bflo(v.z); acc[5] += w * bfhi(v.z);
    acc[6] += w * bflo(v.w); acc[7] += w * bfhi(v.w);
}

#define RPG 2                                    // rows per 8-lane group
#define AGG_RPB (32 * RPG)                       // 64 rows per block
#define AGG_CHUNKS ((N_NODES + AGG_RPB - 1) / AGG_RPB)   // 313
#define AGG_BLOCKS (8 * AGG_CHUNKS)              // 2504

__global__ __launch_bounds__(256) void agg_k(const ushort* __restrict__ s,
                                             const int* __restrict__ rowstart,
                                             const int2* __restrict__ csr_cv,
                                             const float* __restrict__ bias,
                                             ushort* __restrict__ hout,
                                             float* __restrict__ pmax,
                                             float* __restrict__ psum) {
    __shared__ float red[2][4][64];              // [max|sum][wave][ch in slice]
    const int slice = blockIdx.x & 7;            // XCD-pinned channel slice
    const int cidx  = (AGG_CHUNKS - 1) - (int)(blockIdx.x >> 3);  // LPT order
    const int wave = threadIdx.x >> 6, lane = threadIdx.x & 63;
    const int g = lane >> 3, sub = lane & 7;     // group, 16B channel chunk
    const uint4* s4 = (const uint4*)s;
    const size_t sbase = (size_t)slice * 8 + sub;
    uint4* houtp = hout ? (uint4*)hout + slice * 8 + sub : nullptr;
    const float4 b0 = ((const float4*)bias)[slice * 16 + sub * 2];
    const float4 b1 = ((const float4*)bias)[slice * 16 + sub * 2 + 1];
    const int ibase = cidx * AGG_RPB + wave * (8 * RPG) + g * RPG;
    float pm[8] = {}, ps[8] = {};                // pooled max/sum (relu >= 0)

    #pragma unroll
    for (int rr = 0; rr < RPG; ++rr) {
        const int idx = ibase + rr;              // == row (sorted space)
        int beg = 0, end = 0;
        if (idx < N_NODES) {
            beg = rowstart[idx];
            end = rowstart[idx + 1];
        }
        float acc[8] = {};
        int j = beg;
        int2 m0, m1, m2, m3;
        if (j < end) {                           // prime the meta pipeline
            m0 = csr_cv[j];
            m1 = csr_cv[(j + 1 < end) ? j + 1 : end - 1];
            m2 = csr_cv[(j + 2 < end) ? j + 2 : end - 1];
            m3 = csr_cv[(j + 3 < end) ? j + 3 : end - 1];
        }
        while (j < end) {
            const int jn = j + 4;
            const int cl = end - 1;
            int2 n0 = csr_cv[(jn     < end) ? jn     : cl];
            int2 n1 = csr_cv[(jn + 1 < end) ? jn + 1 : cl];
            int2 n2 = csr_cv[(jn + 2 < end) ? jn + 2 : cl];
            int2 n3 = csr_cv[(jn + 3 < end) ? jn + 3 : cl];
            uint4 v0 = s4[(size_t)m0.x * 64 + sbase];
            uint4 v1 = s4[(size_t)m1.x * 64 + sbase];
            uint4 v2 = s4[(size_t)m2.x * 64 + sbase];
            uint4 v3 = s4[(size_t)m3.x * 64 + sbase];
            float w0 = __int_as_float(m0.y);
            float w1 = (j + 1 < end) ? __int_as_float(m1.y) : 0.f;
            float w2 = (j + 2 < end) ? __int_as_float(m2.y) : 0.f;
            float w3 = (j + 3 < end) ? __int_as_float(m3.y) : 0.f;
            fma8(acc, v0, w0);
            fma8(acc, v1, w1);
            fma8(acc, v2, w2);
            fma8(acc, v3, w3);
            m0 = n0; m1 = n1; m2 = n2; m3 = n3;
            j = jn;
        }
        if (idx < N_NODES) {
            float o[8];
            o[0] = fmaxf(acc[0] + b0.x, 0.f); o[1] = fmaxf(acc[1] + b0.y, 0.f);
            o[2] = fmaxf(acc[2] + b0.z, 0.f); o[3] = fmaxf(acc[3] + b0.w, 0.f);
            o[4] = fmaxf(acc[4] + b1.x, 0.f); o[5] = fmaxf(acc[5] + b1.y, 0.f);
            o[6] = fmaxf(acc[6] + b1.z, 0.f); o[7] = fmaxf(acc[7] + b1.w, 0.f);
            #pragma unroll
            for (int i = 0; i < 8; ++i) {
                pm[i] = fmaxf(pm[i], o[i]);
                ps[i] += o[i];
            }
            if (houtp) {
                uint4 ov;
                ov.x = pack2(o[0], o[1]); ov.y = pack2(o[2], o[3]);
                ov.z = pack2(o[4], o[5]); ov.w = pack2(o[6], o[7]);
                houtp[(size_t)idx * 64] = ov;
            }
        }
    }
    // pooled reduce: over 8 groups in wave (lane bits 3..5), then over waves
    #pragma unroll
    for (int off = 8; off <= 32; off <<= 1)
        #pragma unroll
        for (int i = 0; i < 8; ++i) {
            pm[i] = fmaxf(pm[i], __shfl_xor(pm[i], off, 64));
            ps[i] += __shfl_xor(ps[i], off, 64);
        }
    if (g == 0) {
        #pragma unroll
        for (int i = 0; i < 8; ++i) {
            red[0][wave][sub * 8 + i] = pm[i];
            red[1][wave][sub * 8 + i] = ps[i];
        }
    }
    __syncthreads();
    if (threadIdx.x < 64) {
        int ch = threadIdx.x;
        float mx = fmaxf(fmaxf(red[0][0][ch], red[0][1][ch]),
                         fmaxf(red[0][2][ch], red[0][3][ch]));
        float sv = (red[1][0][ch] + red[1][1][ch]) +
                   (red[1][2][ch] + red[1][3][ch]);
        atomicMax((int*)&pmax[slice * 64 + ch], __float_as_int(mx));
        atomicAdd(&psum[slice * 64 + ch], sv);
    }
}

// ---------- pure gemm (layers 2,3; pools now fused into agg) ----------
__global__ __launch_bounds__(256) void gemm_k(const ushort* __restrict__ h,
                                              const ushort* __restrict__ wt,
                                              ushort* __restrict__ s) {
    __shared__ __align__(16) char smem[16384];
    gemm_tile(h, wt, s, nullptr, blockIdx.x, smem);
}

// ---------- head MLP + log_softmax (1024 threads, split-k; proven) ----------
__global__ __launch_bounds__(1024) void mlp_k(const float* __restrict__ pool_max,
                                              const float* __restrict__ pool_sum,
                                              const float* __restrict__ l1W,
                                              const float* __restrict__ l1b,
                                              const float* __restrict__ l2W,
                                              const float* __restrict__ l2b,
                                              const float* __restrict__ l3W,
                                              const float* __restrict__ l3b,
                                              float* __restrict__ out) {
    __shared__ float g[1024];
    __shared__ float part[1024];
    __shared__ float a1[128];
    __shared__ float a2[64];
    __shared__ float a3[10];
    const int tid = threadIdx.x;
    if (tid < 512) {
        g[tid]       = pool_max[tid] + pool_max[512 + tid] + pool_max[1024 + tid];
        g[512 + tid] = (pool_sum[tid] + pool_sum[512 + tid] + pool_sum[1024 + tid]) *
                       (1.0f / N_NODES);
    }
    __syncthreads();
    {
        int ch = tid & 127, sl = tid >> 7;
        float acc = (sl == 0) ? l1b[ch] : 0.f;
        int k0 = sl * 128;
        #pragma unroll 4
        for (int k = k0; k < k0 + 128; ++k) acc += g[k] * l1W[k * 128 + ch];
        part[tid] = acc;
    }
    __syncthreads();
    if (tid < 128) {
        float a = part[tid];
        #pragma unroll
        for (int ss = 1; ss < 8; ++ss) a += part[tid + ss * 128];
        a1[tid] = fmaxf(a, 0.f);
    }
    __syncthreads();
    if (tid < 512) {
        int ch = tid & 63, sl = tid >> 6;
        float acc = (sl == 0) ? l2b[ch] : 0.f;
        int k0 = sl * 16;
        #pragma unroll
        for (int k = k0; k < k0 + 16; ++k) acc += a1[k] * l2W[k * 64 + ch];
        part[tid] = acc;
    }
    __syncthreads();
    if (tid < 64) {
        float a = part[tid];
        #pragma unroll
        for (int ss = 1; ss < 8; ++ss) a += part[tid + ss * 64];
        a2[tid] = fmaxf(a, 0.f);
    }
    __syncthreads();
    if (tid < 10) {
        float acc = l3b[tid];
        for (int k = 0; k < 64; ++k) acc += a2[k] * l3W[k * 10 + tid];
        a3[tid] = acc;
    }
    __syncthreads();
    if (tid == 0) {
        float m = a3[0];
        for (int j = 1; j < 10; ++j) m = fmaxf(m, a3[j]);
        float ssum = 0.f;
        for (int j = 0; j < 10; ++j) ssum += expf(a3[j] - m);
        float lse = m + logf(ssum);
        for (int j = 0; j < 10; ++j) out[j] = a3[j] - lse;
    }
}

extern "C" void kernel_launch(void* const* d_in, const int* in_sizes, int n_in,
                              void* d_out, int out_size, void* d_ws, size_t ws_size,
                              hipStream_t stream) {
    const float* x    = (const float*)d_in[0];
    const int*   rows = (const int*)  d_in[1];
    const int*   cols = (const int*)  d_in[2];
    const float* vals = (const float*)d_in[3];
    const float* W1   = (const float*)d_in[4];
    const float* b1   = (const float*)d_in[5];
    const float* W2   = (const float*)d_in[6];
    const float* b2   = (const float*)d_in[7];
    const float* W3   = (const float*)d_in[8];
    const float* b3   = (const float*)d_in[9];
    const float* l1W  = (const float*)d_in[10];
    const float* l1b  = (const float*)d_in[11];
    const float* l2W  = (const float*)d_in[12];
    const float* l2b  = (const float*)d_in[13];
    const float* l3W  = (const float*)d_in[14];
    const float* l3b  = (const float*)d_in[15];
    float* out = (float*)d_out;

    char* ws = (char*)d_ws;
    size_t off = 0;
    auto alloc = [&](size_t bytes) {
        void* p = ws + off;
        off += (bytes + 255) & ~(size_t)255;
        return p;
    };
    ushort* xb       = (ushort*)alloc((size_t)N_NODES * HD * 2);
    ushort* s        = (ushort*)alloc((size_t)N_NODES * HD * 2);
    ushort* hb       = (ushort*)alloc((size_t)N_NODES * HD * 2);
    ushort* wt1      = (ushort*)alloc((size_t)HD * HD * 2);
    ushort* wt2      = (ushort*)alloc((size_t)HD * HD * 2);
    ushort* wt3      = (ushort*)alloc((size_t)HD * HD * 2);
    // deg/pmax/psum contiguous -> one hipMemsetAsync zeroes all three
    int*    deg      = (int*)   alloc((size_t)N_NODES * 4);      // 80128 pad
    float*  pmax     = (float*) alloc((size_t)3 * 512 * 4);      // 6144
    float*  psum     = (float*) alloc((size_t)3 * 512 * 4);      // 6144
    int*    rowstart = (int*)   alloc((size_t)(N_NODES + 1) * 4);
    int*    cursor   = (int*)   alloc((size_t)N_NODES * 4);
    int2*   csr_cv   = (int2*)  alloc((size_t)N_EDGES * 8);
    int*    inv      = (int*)   alloc((size_t)N_NODES * 4);
    (void)ws_size; (void)in_sizes; (void)n_in; (void)out_size;

    // 0: zero deg+pmax+psum (contiguous: 80128 + 6144 + 6144 bytes)
    hipMemsetAsync(deg, 0, ((size_t)N_NODES * 4 + 255 & ~(size_t)255)
                           + 2 * (((size_t)3 * 512 * 4 + 255) & ~(size_t)255),
                   stream);
    // 1: prep (cvt + wt transpose + edge histogram)
    prep_k<<<NB_CVT + NB_WT + NB_HIST, 256, 0, stream>>>(
        x, xb, W1, W2, W3, wt1, wt2, wt3, rows, deg);
    // 2: degree-sort relabeling (inv) + sorted-space CSR offsets
    scan_k<<<1, 1024, 0, stream>>>(deg, rowstart, cursor, inv);
    // 3: gemm1 (scatter to sorted order) || fill CSR (translated)
    gf1_k<<<628 + 1250, 256, 0, stream>>>(xb, wt1, s, rows, cols, vals, inv,
                                          cursor, csr_cv);
    // 4: agg1 + pool1
    agg_k<<<AGG_BLOCKS, 256, 0, stream>>>(s, rowstart, csr_cv, b1, hb,
                                          pmax, psum);
    // 5: gemm2
    gemm_k<<<628, 256, 0, stream>>>(hb, wt2, s);
    // 6: agg2 + pool2
    agg_k<<<AGG_BLOCKS, 256, 0, stream>>>(s, rowstart, csr_cv, b2, hb,
                                          pmax + 512, psum + 512);
    // 7: gemm3
    gemm_k<<<628, 256, 0, stream>>>(hb, wt3, s);
    // 8: agg3 + pool3 (no hb write -- output only needed for pooling)
    agg_k<<<AGG_BLOCKS, 256, 0, stream>>>(s, rowstart, csr_cv, b3, nullptr,
                                          pmax + 1024, psum + 1024);
    // 9: mlp head
    mlp_k<<<1, 1024, 0, stream>>>(pmax, psum, l1W, l1b, l2W, l2b, l3W, l3b, out);
}